// Round 1
// baseline (606.135 us; speedup 1.0000x reference)
//
#include <hip/hip_runtime.h>

#define D    3072
#define H1   32
#define H2   32
#define OUTD 10
#define NEG  0.01f

// ---------------------------------------------------------------------------
// Prep: wT[k][j] = w1[j][k]  (3072x32, contiguous 128B per k -> s_load'able)
//       s1[j]    = sum_k w1[j][k]
// ---------------------------------------------------------------------------
__global__ void prep_kernel(const float* __restrict__ w1,
                            float* __restrict__ wt,
                            float* __restrict__ s1) {
    const int j = blockIdx.x;    // 0..31
    const int t = threadIdx.x;   // 0..255
    float s = 0.f;
    for (int k = t; k < D; k += 256) {
        float v = w1[j * D + k];          // coalesced read along k
        wt[(size_t)k * H1 + j] = v;       // scattered write (tiny, one-time)
        s += v;
    }
    __shared__ float red[256];
    red[t] = s;
    __syncthreads();
    for (int off = 128; off > 0; off >>= 1) {
        if (t < off) red[t] += red[t + off];
        __syncthreads();
    }
    if (t == 0) s1[j] = red[0];
}

// ---------------------------------------------------------------------------
// Fused: rownorm + 3-layer MLP + LeakyReLU, one pass over x.
// Block = 256 thr: lane (tid&63) -> row, wave (tid>>6) -> k-quarter (768 k).
// w values are wave-uniform -> SGPR loads; x per-lane dwordx4.
// ---------------------------------------------------------------------------
__global__ __launch_bounds__(256, 4) void fused_kernel(
    const float* __restrict__ x,
    const float* __restrict__ wt,
    const float* __restrict__ s1,
    const float* __restrict__ b1,
    const float* __restrict__ w2,
    const float* __restrict__ b2,
    const float* __restrict__ w3,
    const float* __restrict__ b3,
    float* __restrict__ out)
{
    const int tid  = threadIdx.x;
    const int lane = tid & 63;
    // readfirstlane: provably wave-uniform so w-pointer arithmetic stays scalar
    const int wv   = __builtin_amdgcn_readfirstlane(tid >> 6);
    const int row  = blockIdx.x * 64 + lane;
    const int KQ   = D / 4;          // 768 k per wave
    const int k0   = wv * KQ;

    const float4* __restrict__ xp = (const float4*)(x + (size_t)row * D + k0);
    const float*  __restrict__ wk = wt + (size_t)k0 * H1;

    float acc[H1];
#pragma unroll
    for (int j = 0; j < H1; ++j) acc[j] = 0.f;
    float s = 0.f, ss = 0.f;

    for (int i = 0; i < KQ / 4; i += 4) {   // 48 iters, 16 k each
        float4 v0 = xp[i + 0];
        float4 v1 = xp[i + 1];
        float4 v2 = xp[i + 2];
        float4 v3 = xp[i + 3];
        float xv[16] = {v0.x, v0.y, v0.z, v0.w,
                        v1.x, v1.y, v1.z, v1.w,
                        v2.x, v2.y, v2.z, v2.w,
                        v3.x, v3.y, v3.z, v3.w};
#pragma unroll
        for (int kk = 0; kk < 16; ++kk) {
            float xk = xv[kk];
            s += xk;
            ss = fmaf(xk, xk, ss);
            const float* __restrict__ wrow = wk + (size_t)(i * 4 + kk) * H1;
#pragma unroll
            for (int j = 0; j < H1; ++j)
                acc[j] = fmaf(xk, wrow[j], acc[j]);   // v,v,s,v : 1 SGPR ok
        }
    }

    // ---- cross-wave reduction via LDS (stride 36 keeps 16B alignment) ----
    __shared__ float part[256 * 36];
    float* my = &part[tid * 36];
#pragma unroll
    for (int j = 0; j < H1; ++j) my[j] = acc[j];
    my[32] = s;
    my[33] = ss;
    __syncthreads();

    if (tid < 64) {
        const int r = blockIdx.x * 64 + tid;
        float dot[H1];
#pragma unroll
        for (int j = 0; j < H1; ++j) dot[j] = 0.f;
        float S = 0.f, SS = 0.f;
#pragma unroll
        for (int w = 0; w < 4; ++w) {
            const float* p = &part[(w * 64 + tid) * 36];
#pragma unroll
            for (int j = 0; j < H1; ++j) dot[j] += p[j];
            S  += p[32];
            SS += p[33];
        }
        const float mean    = S * (1.f / D);
        const float var     = (SS - S * S * (1.f / D)) * (1.f / (D - 1));
        const float inv_std = rsqrtf(var);

        float y1[H1];
#pragma unroll
        for (int j = 0; j < H1; ++j) {
            float v = (dot[j] - mean * s1[j]) * inv_std + b1[j];
            y1[j] = (v >= 0.f) ? v : NEG * v;
        }
        float y2[H2];
#pragma unroll
        for (int j = 0; j < H2; ++j) {
            float a = b2[j];
            const float* wr = w2 + j * H1;     // uniform -> s_load
#pragma unroll
            for (int i2 = 0; i2 < H1; ++i2) a = fmaf(wr[i2], y1[i2], a);
            y2[j] = (a >= 0.f) ? a : NEG * a;
        }
#pragma unroll
        for (int j = 0; j < OUTD; ++j) {
            float a = b3[j];
            const float* wr = w3 + j * H2;     // uniform -> s_load
#pragma unroll
            for (int i2 = 0; i2 < H2; ++i2) a = fmaf(wr[i2], y2[i2], a);
            a = (a >= 0.f) ? a : NEG * a;
            out[(size_t)r * OUTD + j] = a;
        }
    }
}

// ---------------------------------------------------------------------------
extern "C" void kernel_launch(void* const* d_in, const int* in_sizes, int n_in,
                              void* d_out, int out_size, void* d_ws, size_t ws_size,
                              hipStream_t stream) {
    const float* x  = (const float*)d_in[0];
    const float* w1 = (const float*)d_in[1];
    const float* b1 = (const float*)d_in[2];
    const float* w2 = (const float*)d_in[3];
    const float* b2 = (const float*)d_in[4];
    const float* w3 = (const float*)d_in[5];
    const float* b3 = (const float*)d_in[6];
    float* out = (float*)d_out;

    const int B = in_sizes[0] / D;           // 32768

    float* wt = (float*)d_ws;                // D*H1 floats = 384 KB
    float* s1 = wt + (size_t)D * H1;         // +32 floats

    prep_kernel<<<H1, 256, 0, stream>>>(w1, wt, s1);
    fused_kernel<<<B / 64, 256, 0, stream>>>(x, wt, s1, b1, w2, b2, w3, b3, out);
}